// Round 7
// baseline (53.661 us; speedup 1.0000x reference)
//
#include <hip/hip_runtime.h>

// LIF_BTN: y[t] = heaviside(tau*v[t-1] + x[t] - v_th), v[t] = (spike ? 0 : m)
// x: [T=32, B=32, N=32768] f32; y same shape/dtype.
//
// ROOFLINE ANALYSIS (R6, final): compulsory DATA-FABRIC traffic is
// 134 MB x-reads (read-once, zero reuse -> L2 useless, Infinity-Cache hits
// still traverse fabric) + 134 MB y-writes = 268 MB at the measured mixed
// (1:1 R:W) fabric ceiling of 6.29 TB/s (D2D-copy ubench) -> floor 42.6 us.
// This kernel: 43.9 us = 97% of roofline.
//
// Config (best of R0-R5 sweep):
//  - float2/thread -> 8192 waves = 32 waves/CU (HW max TLP); float4 (R0) gave
//    only 16 waves/CU and was latency-bound; VGPR=24 keeps full occupancy.
//  - chunk-8 double-buffered prefetch: 8 loads in flight per wave; chunk-16
//    (R4, -20%) bulk-phases the DRAM direction turnaround; rotate-8 (R5, -5%)
//    and asm-pinned stores (R3, -18%) defeat the compiler scheduler.
//  - __builtin_nontemporal_store for the write-once y stream (R1: removed
//    33 MB of RFO/allocate traffic vs plain store).
//  - FETCH_SIZE floor ~65.6 MB (= x/2) is harness-imposed: 537 MB memsets
//    between replays evict half of x from the 256 MB L3; sc0/sc1/nt store
//    bypass (R3) proved stores are NOT the evictor.

typedef float f32x2 __attribute__((ext_vector_type(2)));

#define T_STEPS 32
#define CHUNK 8
#define TAU 0.5f
#define V_TH 1.0f

__global__ __launch_bounds__(256) void lif_btn_kernel(
    const f32x2* __restrict__ x, f32x2* __restrict__ y, int n2) {
    int idx = blockIdx.x * blockDim.x + threadIdx.x;
    if (idx >= n2) return;

    const f32x2* xp = x + idx;
    f32x2* yp = y + idx;

    f32x2 v;
    v.x = 0.f; v.y = 0.f;

    f32x2 cur[CHUNK], nxt[CHUNK];

    #pragma unroll
    for (int i = 0; i < CHUNK; ++i)
        cur[i] = xp[(size_t)i * n2];

    #pragma unroll
    for (int c = 0; c < T_STEPS / CHUNK; ++c) {
        if (c + 1 < T_STEPS / CHUNK) {
            #pragma unroll
            for (int i = 0; i < CHUNK; ++i)
                nxt[i] = xp[(size_t)((c + 1) * CHUNK + i) * n2];
        }
        #pragma unroll
        for (int i = 0; i < CHUNK; ++i) {
            f32x2 m, out;
            m.x = TAU * v.x + cur[i].x;
            m.y = TAU * v.y + cur[i].y;
            out.x = (m.x >= V_TH) ? 1.f : 0.f;
            out.y = (m.y >= V_TH) ? 1.f : 0.f;
            v.x = (m.x >= V_TH) ? 0.f : m.x;
            v.y = (m.y >= V_TH) ? 0.f : m.y;
            __builtin_nontemporal_store(out, yp + (size_t)(c * CHUNK + i) * n2);
        }
        #pragma unroll
        for (int i = 0; i < CHUNK; ++i)
            cur[i] = nxt[i];
    }
}

extern "C" void kernel_launch(void* const* d_in, const int* in_sizes, int n_in,
                              void* d_out, int out_size, void* d_ws, size_t ws_size,
                              hipStream_t stream) {
    const float* x = (const float*)d_in[0];
    float* y = (float*)d_out;

    int total = in_sizes[0];        // T*B*N = 33554432
    int per_t = total / T_STEPS;    // B*N   = 1048576
    int n2 = per_t / 2;             // 524288 float2 chains

    const int block = 256;
    int grid = (n2 + block - 1) / block;  // 2048 blocks -> 32 waves/CU
    lif_btn_kernel<<<grid, block, 0, stream>>>(
        (const f32x2*)x, (f32x2*)y, n2);
}